// Round 14
// baseline (48.109 us; speedup 1.0000x reference)
//
#include <hip/hip_runtime.h>
#include <hip/hip_fp16.h>
#include <math.h>

// (B,Tq,Tk,U) = (32,1024,1024,256), f32 in/out.
#define NB 32
#define TQ 1024
#define TK 1024
#define UD 256

typedef __attribute__((ext_vector_type(8))) _Float16 f16x8;
typedef __attribute__((ext_vector_type(4))) _Float16 f16x4;
typedef __attribute__((ext_vector_type(4))) float f32x4;

__device__ __forceinline__ float fast_tanh(float x) {
  const float e = __expf(2.0f * x);
  return 1.0f - 2.0f / (e + 1.0f);
}

// ---------------------------------------------------------------------------
// K0: Wq f32 -> f16, k-slot-major: wq16t[ks][u][8] (ks = k>>3).
// ---------------------------------------------------------------------------
__global__ __launch_bounds__(256) void cvt_wq_kernel(
    const float* __restrict__ Wq, _Float16* __restrict__ wq16t) {
  const int idx = blockIdx.x * 256 + threadIdx.x;  // 8192
  const int u = idx >> 5;
  const int ks = idx & 31;
  const float4 w0 = *reinterpret_cast<const float4*>(Wq + u * UD + ks * 8);
  const float4 w1 = *reinterpret_cast<const float4*>(Wq + u * UD + ks * 8 + 4);
  f16x8 h;
  h[0] = (_Float16)w0.x; h[1] = (_Float16)w0.y;
  h[2] = (_Float16)w0.z; h[3] = (_Float16)w0.w;
  h[4] = (_Float16)w1.x; h[5] = (_Float16)w1.y;
  h[6] = (_Float16)w1.z; h[7] = (_Float16)w1.w;
  *reinterpret_cast<f16x8*>(wq16t + ((size_t)ks * 256 + u) * 8) = h;
}

// ---------------------------------------------------------------------------
// K1: sk[r] = sum_u v[u] * tanh( sum_c key[r,c] * Wq[u,c] )   (MFMA f16)
// 1024 blocks x 256 thr (4 waves; wave wc = u quarter). 32 rows/block.
// A: one-time stage, 1 KB contiguous row-loads per wave, cvt->f16, k-slot-
//    major LDS As[ks][row ^ ((ks&3)<<2)][8]  (16 KB only).
// B: REGISTER-resident per K-quarter (8 x f16x8 = 32 VGPR), reloaded from
//    L2-hot wq16t; fully unrolled (static indexing).
// K-loop is BARRIER-FREE (one barrier after A-stage, one in epilogue).
// __launch_bounds__(256,4): up to 4 blocks/CU -> cold fetch overlaps compute.
// ---------------------------------------------------------------------------
__global__ __launch_bounds__(256, 4) void sk_mfma_kernel(
    const float* __restrict__ key, const _Float16* __restrict__ wq16t,
    const float* __restrict__ v, float* __restrict__ sk) {
  __shared__ _Float16 As[32 * 32 * 8];  // 16 KB: [ks][row^sw][8]

  const int tid = threadIdx.x;
  const int lane = tid & 63;
  const int wc = tid >> 6;  // 0..3: u quarter
  const int lx = lane & 15;
  const int lg = lane >> 4;
  const int row0 = blockIdx.x * 32;

  // ---- stage A once: wave wc loads rows wc*8..+7 (1 KB contiguous each) ----
  {
    const int ks = lane >> 1;  // k-slot covered by this lane's 4 floats
    const int jh = lane & 1;   // half within the 8-f16 slot
#pragma unroll
    for (int i = 0; i < 8; ++i) {
      const int r = wc * 8 + i;
      const float4 a = *reinterpret_cast<const float4*>(
          key + (size_t)(row0 + r) * UD + lane * 4);
      f16x4 h;
      h[0] = (_Float16)a.x; h[1] = (_Float16)a.y;
      h[2] = (_Float16)a.z; h[3] = (_Float16)a.w;
      const int rs = r ^ ((ks & 3) << 2);
      *reinterpret_cast<f16x4*>(As + ((ks * 32 + rs) * 8 + jh * 4)) = h;
    }
  }
  __syncthreads();

  float vv[4];
#pragma unroll
  for (int n = 0; n < 4; ++n) vv[n] = v[wc * 64 + n * 16 + lx];

  f32x4 acc[2][4];
#pragma unroll
  for (int m = 0; m < 2; ++m)
#pragma unroll
    for (int n = 0; n < 4; ++n) acc[m][n] = (f32x4){0.f, 0.f, 0.f, 0.f};

  // ---- K-loop: 4 quarters x (load 8 B-frags to regs; 2 kq x 8 MFMA) ----
#pragma unroll
  for (int q = 0; q < 4; ++q) {
    f16x8 bf[2][4];
#pragma unroll
    for (int kq = 0; kq < 2; ++kq)
#pragma unroll
      for (int n = 0; n < 4; ++n) {
        const int ks = q * 8 + kq * 4 + lg;
        bf[kq][n] = *reinterpret_cast<const f16x8*>(
            wq16t + ((size_t)ks * 256 + wc * 64 + n * 16 + lx) * 8);
      }
#pragma unroll
    for (int kq = 0; kq < 2; ++kq) {
      const int ks = q * 8 + kq * 4 + lg;
      f16x8 af[2];
#pragma unroll
      for (int m = 0; m < 2; ++m) {
        const int rs = (m * 16 + lx) ^ ((ks & 3) << 2);
        af[m] = *reinterpret_cast<const f16x8*>(As + (ks * 32 + rs) * 8);
      }
#pragma unroll
      for (int m = 0; m < 2; ++m)
#pragma unroll
        for (int n = 0; n < 4; ++n)
          acc[m][n] = __builtin_amdgcn_mfma_f32_16x16x32_f16(
              af[m], bf[kq][n], acc[m][n], 0, 0, 0);
    }
  }

  // ---- epilogue: tanh, dot v, shfl-reduce over lx, LDS-reduce over wc ----
  // acc[m][n] reg r: row_local = m*16 + lg*4 + r ; u = wc*64 + n*16 + lx
  float* red = (float*)As;  // As free after this point (one barrier below)
  float part[2][4];
#pragma unroll
  for (int m = 0; m < 2; ++m)
#pragma unroll
    for (int r = 0; r < 4; ++r) part[m][r] = 0.f;
#pragma unroll
  for (int m = 0; m < 2; ++m)
#pragma unroll
    for (int n = 0; n < 4; ++n)
#pragma unroll
      for (int r = 0; r < 4; ++r)
        part[m][r] += vv[n] * fast_tanh(acc[m][n][r]);

  __syncthreads();  // everyone done reading As
#pragma unroll
  for (int m = 0; m < 2; ++m)
#pragma unroll
    for (int r = 0; r < 4; ++r) {
      float s = part[m][r];
      s += __shfl_xor(s, 1);
      s += __shfl_xor(s, 2);
      s += __shfl_xor(s, 4);
      s += __shfl_xor(s, 8);
      if (lx == 0) red[(m * 16 + lg * 4 + r) * 4 + wc] = s;
    }
  __syncthreads();
  if (tid < 32) {
    sk[row0 + tid] = red[tid * 4 + 0] + red[tid * 4 + 1] + red[tid * 4 + 2] +
                     red[tid * 4 + 3];
  }
}

// ---------------------------------------------------------------------------
// K2: fused softmax + PV partial (proven: ~7.5 us). Block (b,ch).
// ---------------------------------------------------------------------------
__global__ __launch_bounds__(256) void pv_kernel(
    const float* __restrict__ sk, const int* __restrict__ vlen,
    const float* __restrict__ value, float* __restrict__ part) {
  const int b = blockIdx.x >> 4;
  const int ch = blockIdx.x & 15;
  const int tid = threadIdx.x;
  const int vl = vlen[b];
  __shared__ float wbuf[64];
  __shared__ float red4[8];
  const float* skb = sk + b * TK;

  if (vl == 0) {  // uniform softmax over the constant-fill row
    if (tid < 64) wbuf[tid] = 1.0f / (float)TK;
  } else {
    float m = -1e30f;
#pragma unroll
    for (int idx = 0; idx < 4; ++idx) {
      const int k = tid + idx * 256;
      if (k < vl) m = fmaxf(m, skb[k]);
    }
    for (int off = 1; off < 64; off <<= 1) m = fmaxf(m, __shfl_xor(m, off));
    if ((tid & 63) == 0) red4[tid >> 6] = m;
    __syncthreads();
    m = fmaxf(fmaxf(red4[0], red4[1]), fmaxf(red4[2], red4[3]));
    float zs = 0.f;
#pragma unroll
    for (int idx = 0; idx < 4; ++idx) {
      const int k = tid + idx * 256;
      zs += (k < vl) ? __expf(skb[k] - m) : 0.f;
    }
    for (int off = 1; off < 64; off <<= 1) zs += __shfl_xor(zs, off);
    if ((tid & 63) == 0) red4[4 + (tid >> 6)] = zs;
    __syncthreads();
    const float rz = 1.0f / (red4[4] + red4[5] + red4[6] + red4[7]);
    if (tid < 64) {
      const int k = ch * 64 + tid;
      wbuf[tid] = (k < vl) ? __expf(skb[k] - m) * rz : 0.f;
    }
  }
  __syncthreads();

  const int d = tid;
  const float* vb = value + ((size_t)b * TK + ch * 64) * UD;
  float acc = 0.f;
#pragma unroll 8
  for (int k = 0; k < 64; ++k)
    acc = fmaf(wbuf[k], vb[(size_t)k * UD + d], acc);
  part[(size_t)(b * 16 + ch) * UD + d] = acc;
}

// ---------------------------------------------------------------------------
// K3: reduce 16 partials -> out_row, broadcast over 64 q rows/block (~6.5 us).
// ---------------------------------------------------------------------------
__global__ __launch_bounds__(256) void bcast_kernel(
    const float* __restrict__ part, float* __restrict__ out) {
  const int b = blockIdx.x >> 4;
  const int qc = blockIdx.x & 15;
  const int tid = threadIdx.x;
  const int qoff = tid >> 6;      // 0..3
  const int dd = (tid & 63) * 4;  // 0..252

  float4 s = make_float4(0.f, 0.f, 0.f, 0.f);
#pragma unroll
  for (int c = 0; c < 16; ++c) {
    const float4 p = *reinterpret_cast<const float4*>(
        &part[(size_t)(b * 16 + c) * UD + dd]);
    s.x += p.x; s.y += p.y; s.z += p.z; s.w += p.w;
  }

  float* ob = out + (size_t)b * TQ * UD + (size_t)qc * 64 * UD;
#pragma unroll 4
  for (int q4 = 0; q4 < 16; ++q4) {
    *reinterpret_cast<float4*>(&ob[(size_t)(q4 * 4 + qoff) * UD + dd]) = s;
  }
}

// ---------------------------------------------------------------------------
extern "C" void kernel_launch(void* const* d_in, const int* in_sizes, int n_in,
                              void* d_out, int out_size, void* d_ws,
                              size_t ws_size, hipStream_t stream) {
  // inputs: 0 query, 1 key, 2 value, 3 valid_length, 4 W_k, 5 W_q, 6 v
  const float* key = (const float*)d_in[1];
  const float* value = (const float*)d_in[2];
  const int* vlen = (const int*)d_in[3];
  const float* Wq = (const float*)d_in[5];
  const float* v = (const float*)d_in[6];
  float* out = (float*)d_out;

  char* ws = (char*)d_ws;
  _Float16* wq16t = (_Float16*)(ws);    // 128 KB (k-slot-major f16 Wq)
  float* sk = (float*)(ws + 131072);    // 128 KB
  float* part = (float*)(ws + 262144);  // 512 KB

  cvt_wq_kernel<<<32, 256, 0, stream>>>(Wq, wq16t);
  sk_mfma_kernel<<<(NB * TK) / 32, 256, 0, stream>>>(key, wq16t, v, sk);
  pv_kernel<<<NB * 16, 256, 0, stream>>>(sk, vlen, value, part);
  bcast_kernel<<<NB * 16, 256, 0, stream>>>(part, out);
}